// Round 13
// baseline (90.116 us; speedup 1.0000x reference)
//
#include <hip/hip_runtime.h>

typedef __attribute__((ext_vector_type(8))) short short8;
typedef __attribute__((ext_vector_type(4))) float f32x4;

#define EPSF 1e-5f
#define NSEQ 4096
#define R_TOT 8192

__device__ __forceinline__ float bf2f(unsigned short u){
  union { unsigned int i; float f; } v; v.i = ((unsigned int)u) << 16; return v.f;
}
__device__ __forceinline__ unsigned short f2bf(float f){
  union { float f; unsigned int i; } v; v.f = f;
  unsigned int u = v.i;
  u += 0x7FFFu + ((u >> 16) & 1u);          // RNE
  return (unsigned short)(u >> 16);
}
__device__ __forceinline__ float wsum(float v){
  #pragma unroll
  for (int o = 32; o > 0; o >>= 1) v += __shfl_xor(v, o, 64);
  return v;
}
// fast tanh-GELU: tanh(y) = 1 - 2/(exp(2y)+1); inf-safe at both tails
__device__ __forceinline__ float gelu_tanh(float x){
  float y = 0.7978845608028654f * (x + 0.044715f * x * x * x);
  float e = __expf(2.0f * y);
  float th = 1.0f - 2.0f / (e + 1.0f);
  return 0.5f * x * (1.0f + th);
}
__device__ __forceinline__ void gload_lds16(const unsigned short* g, unsigned short* l){
  __builtin_amdgcn_global_load_lds(
      (const __attribute__((address_space(1))) unsigned int*)g,
      (__attribute__((address_space(3))) unsigned int*)l, 16, 0, 0);
}

// ------ prep: x->bf16 (0..2047) + 4 weight transposes (2048..2239) ----------------
__global__ void k_prep(const float* __restrict__ x, unsigned short* __restrict__ xbf,
                       const float* __restrict__ w_qkv, const float* __restrict__ w_ao,
                       const float* __restrict__ w_fc1, const float* __restrict__ w_fc2,
                       unsigned short* __restrict__ oq, unsigned short* __restrict__ oa,
                       unsigned short* __restrict__ o1, unsigned short* __restrict__ o2)
{
  int bid = blockIdx.x;
  const int t = threadIdx.x;
  if (bid < 2048){
    int i = (bid * 256 + t) * 4;
    float4 v = *(const float4*)(x + i);
    ushort4 o;
    o.x = f2bf(v.x); o.y = f2bf(v.y); o.z = f2bf(v.z); o.w = f2bf(v.w);
    *(ushort4*)(xbf + i) = o;
    return;
  }
  bid -= 2048;
  const float* in; unsigned short* out; int rows, cols, tid;
  if (bid < 48)      { in = w_qkv; out = oq; rows = 256;  cols = 768;  tid = bid; }
  else if (bid < 64) { in = w_ao;  out = oa; rows = 256;  cols = 256;  tid = bid - 48; }
  else if (bid < 128){ in = w_fc1; out = o1; rows = 256;  cols = 1024; tid = bid - 64; }
  else               { in = w_fc2; out = o2; rows = 1024; cols = 256;  tid = bid - 128; }
  const int tC = cols >> 6;
  const int r0 = (tid / tC) * 64, c0 = (tid % tC) * 64;
  __shared__ float tile[64][68];
  const int i = t >> 4, j4 = (t & 15) * 4;
  #pragma unroll
  for (int p = 0; p < 4; p++){
    float4 v = *(const float4*)(in + (size_t)(r0 + i + p * 16) * cols + c0 + j4);
    tile[i + p * 16][j4 + 0] = v.x; tile[i + p * 16][j4 + 1] = v.y;
    tile[i + p * 16][j4 + 2] = v.z; tile[i + p * 16][j4 + 3] = v.w;
  }
  __syncthreads();
  #pragma unroll
  for (int p = 0; p < 4; p++){
    int ci = i + p * 16;
    ushort4 o;
    o.x = f2bf(tile[j4 + 0][ci]); o.y = f2bf(tile[j4 + 1][ci]);
    o.z = f2bf(tile[j4 + 2][ci]); o.w = f2bf(tile[j4 + 3][ci]);
    *(ushort4*)(out + (size_t)(c0 + ci) * rows + r0 + j4) = o;
  }
}

// -------- bf16 MFMA GEMM, 2-phase double-buffered staging (T3-minimum) ------------
template<int BM, int BN, bool HAS_BIAS, bool DO_GELU, bool OUT_BF16>
__global__ __launch_bounds__(256) void k_gemm(const unsigned short* __restrict__ A,
                       const unsigned short* __restrict__ BT,
                       const float* __restrict__ bias,
                       float* __restrict__ Cf,
                       unsigned short* __restrict__ Cb,
                       int M, int N, int K)
{
  constexpr int BK = 64;
  constexpr int FM = BM / 32, FN = BN / 32;
  __shared__ unsigned short As[2][BM * BK];
  __shared__ unsigned short Bs[2][BN * BK];
  const int t  = threadIdx.x;
  const int l  = t & 63;
  const int w  = t >> 6;
  const int wm = w >> 1, wn = w & 1;
  const int lr = l & 15, kq = l >> 4;
  const int m0 = blockIdx.y * BM, n0 = blockIdx.x * BN;

  f32x4 acc[FM][FN];
  #pragma unroll
  for (int i = 0; i < FM; i++)
    #pragma unroll
    for (int j = 0; j < FN; j++) acc[i][j] = (f32x4){0.f, 0.f, 0.f, 0.f};

  const int crow = l >> 3, ccolE = (l & 7) * 8;
  const int nk = K / BK;

  auto stage = [&](int s, int bsel){
    #pragma unroll
    for (int c = w; c < BM / 8; c += 4)
      gload_lds16(A  + (size_t)(m0 + c * 8 + crow) * K + s * BK + ccolE, &As[bsel][c * 512]);
    #pragma unroll
    for (int c = w; c < BN / 8; c += 4)
      gload_lds16(BT + (size_t)(n0 + c * 8 + crow) * K + s * BK + ccolE, &Bs[bsel][c * 512]);
  };

  stage(0, 0);
  __syncthreads();
  for (int s = 0; s < nk; ++s){
    const int cur = s & 1;
    if (s + 1 < nk) stage(s + 1, cur ^ 1);
    #pragma unroll
    for (int kk = 0; kk < BK; kk += 32){
      short8 af[FM], bfr[FN];
      #pragma unroll
      for (int i = 0; i < FM; i++)
        af[i]  = *(const short8*)&As[cur][(wm * (BM / 2) + i * 16 + lr) * 64 + kk + kq * 8];
      #pragma unroll
      for (int j = 0; j < FN; j++)
        bfr[j] = *(const short8*)&Bs[cur][(wn * (BN / 2) + j * 16 + lr) * 64 + kk + kq * 8];
      #pragma unroll
      for (int i = 0; i < FM; i++)
        #pragma unroll
        for (int j = 0; j < FN; j++)
          acc[i][j] = __builtin_amdgcn_mfma_f32_16x16x32_bf16(af[i], bfr[j], acc[i][j], 0, 0, 0);
    }
    __syncthreads();
  }

  const int row0 = m0 + wm * (BM / 2);
  const int col0 = n0 + wn * (BN / 2);
  #pragma unroll
  for (int i = 0; i < FM; i++){
    #pragma unroll
    for (int j = 0; j < FN; j++){
      #pragma unroll
      for (int r = 0; r < 4; r++){
        int row = row0 + i * 16 + kq * 4 + r;
        int col = col0 + j * 16 + lr;
        float v = acc[i][j][r];
        if (HAS_BIAS) v += bias[col];
        if (DO_GELU)  v = gelu_tanh(v);
        if (OUT_BF16) Cb[(size_t)row * N + col] = f2bf(v);
        else          Cf[(size_t)row * N + col] = v;
      }
    }
  }
}

// ---- MFMA M-sum: Spart[sl][bh][e][d] = sum over 128 rows of exp(k[n,e]) q[n,d] ----
// grid (32,8); 2 chunks of 64 rows accumulated in registers. Ones-row appended to
// qT gives the softmax denominator as C-tile j=4.
#define NPAD 72
__global__ __launch_bounds__(256) void k_msum(const unsigned short* __restrict__ qkv,
                                              float* __restrict__ Spart,
                                              float* __restrict__ dsum_part)
{
  __shared__ unsigned short kT[64 * NPAD];
  __shared__ unsigned short qT[80 * NPAD];
  const int t = threadIdx.x;          // 0..255
  const int sl = blockIdx.x;          // 0..31
  const int bh = blockIdx.y;          // 0..7
  const int b = bh >> 2, h = bh & 3;
  const int e4 = (t & 15) * 4;
  const int col = (t >> 4) * 4;       // 0,4,...,60
  const int w4 = t >> 6, lr = t & 15, kq = (t >> 4) & 3;

  f32x4 acc[5];
  #pragma unroll
  for (int j = 0; j < 5; ++j) acc[j] = (f32x4){0.f, 0.f, 0.f, 0.f};

  for (int ch = 0; ch < 2; ++ch){
    int n = sl * 128 + ch * 64 + col;
    const unsigned short* rp = qkv + (size_t)(b * NSEQ + n) * 768 + h * 64 + e4;
    ushort4 q0 = *(const ushort4*)(rp);
    ushort4 q1 = *(const ushort4*)(rp + 768);
    ushort4 q2 = *(const ushort4*)(rp + 1536);
    ushort4 q3 = *(const ushort4*)(rp + 2304);
    ushort4 k0 = *(const ushort4*)(rp + 256);
    ushort4 k1 = *(const ushort4*)(rp + 1024);
    ushort4 k2 = *(const ushort4*)(rp + 1792);
    ushort4 k3 = *(const ushort4*)(rp + 2560);
    if (ch) __syncthreads();          // prior MFMA reads complete
    ushort4 w;
    w.x = q0.x; w.y = q1.x; w.z = q2.x; w.w = q3.x; *(ushort4*)&qT[(e4+0)*NPAD + col] = w;
    w.x = q0.y; w.y = q1.y; w.z = q2.y; w.w = q3.y; *(ushort4*)&qT[(e4+1)*NPAD + col] = w;
    w.x = q0.z; w.y = q1.z; w.z = q2.z; w.w = q3.z; *(ushort4*)&qT[(e4+2)*NPAD + col] = w;
    w.x = q0.w; w.y = q1.w; w.z = q2.w; w.w = q3.w; *(ushort4*)&qT[(e4+3)*NPAD + col] = w;
    w.x = f2bf(__expf(bf2f(k0.x))); w.y = f2bf(__expf(bf2f(k1.x)));
    w.z = f2bf(__expf(bf2f(k2.x))); w.w = f2bf(__expf(bf2f(k3.x)));
    *(ushort4*)&kT[(e4+0)*NPAD + col] = w;
    w.x = f2bf(__expf(bf2f(k0.y))); w.y = f2bf(__expf(bf2f(k1.y)));
    w.z = f2bf(__expf(bf2f(k2.y))); w.w = f2bf(__expf(bf2f(k3.y)));
    *(ushort4*)&kT[(e4+1)*NPAD + col] = w;
    w.x = f2bf(__expf(bf2f(k0.z))); w.y = f2bf(__expf(bf2f(k1.z)));
    w.z = f2bf(__expf(bf2f(k2.z))); w.w = f2bf(__expf(bf2f(k3.z)));
    *(ushort4*)&kT[(e4+2)*NPAD + col] = w;
    w.x = f2bf(__expf(bf2f(k0.w))); w.y = f2bf(__expf(bf2f(k1.w)));
    w.z = f2bf(__expf(bf2f(k2.w))); w.w = f2bf(__expf(bf2f(k3.w)));
    *(ushort4*)&kT[(e4+3)*NPAD + col] = w;
    if (ch == 0 && t < 16){
      ushort4 ones; ones.x = 0x3F80; ones.y = 0x3F80; ones.z = 0x3F80; ones.w = 0x3F80;
      *(ushort4*)&qT[64 * NPAD + t * 4] = ones;
    }
    __syncthreads();
    #pragma unroll
    for (int ks = 0; ks < 2; ++ks){
      int nc = ks * 32 + kq * 8;
      short8 af = *(const short8*)&kT[(w4 * 16 + lr) * NPAD + nc];
      #pragma unroll
      for (int j = 0; j < 5; ++j){
        short8 bf = *(const short8*)&qT[(j * 16 + lr) * NPAD + nc];
        acc[j] = __builtin_amdgcn_mfma_f32_16x16x32_bf16(af, bf, acc[j], 0, 0, 0);
      }
    }
  }
  float* sp = Spart + ((size_t)sl * 8 + bh) * 4096;
  #pragma unroll
  for (int j = 0; j < 4; ++j)
    #pragma unroll
    for (int r = 0; r < 4; ++r)
      sp[(w4 * 16 + kq * 4 + r) * 64 + j * 16 + lr] = acc[j][r];
  if (lr == 0){
    float* dp = dsum_part + (sl * 8 + bh) * 64;
    #pragma unroll
    for (int r = 0; r < 4; ++r) dp[w4 * 16 + kq * 4 + r] = acc[4][r];
  }
}

// ------ fused: reduce Spart(32) -> M' -> A = v@M' -> y = A@w_ao + b_ao -> dLN ----
__global__ __launch_bounds__(256) void k_projvm_dln(
    const unsigned short* __restrict__ qkv,
    const float* __restrict__ Spart, const float* __restrict__ dsum_part,
    const unsigned short* __restrict__ waoT,
    const float* __restrict__ bias, const float* __restrict__ x,
    const float* __restrict__ g_ao, const float* __restrict__ be_ao,
    const float* __restrict__ g1, const float* __restrict__ be1,
    unsigned short* __restrict__ hbf, float* __restrict__ sxh)
{
  // LDS: As[32][264] | vlds[128][64] | mt[64][64] | Bs{0,1}[256][64] (yt aliases Bs)
  __shared__ __align__(16) char smem[16896 + 16384 + 8192 + 65536];
  unsigned short* As   = (unsigned short*)smem;                       // stride 264
  unsigned short* vlds = (unsigned short*)(smem + 16896);
  unsigned short* mt   = (unsigned short*)(smem + 16896 + 16384);
  unsigned short* Bs0  = (unsigned short*)(smem + 41472);             // +bsel*16384 shorts
  float*          yt   = (float*)(smem + 41472);

  const int t = threadIdx.x, l = t & 63, w = t >> 6;
  const int lr = l & 15, kq = l >> 4;
  const int m0 = blockIdx.x * 32;
  const int b = m0 >> 12, h = (m0 >> 10) & 3;
  const int bh = b * 4 + h;
  const int n0 = (m0 & 1023) * 4;
  const int crow = l >> 3, ccolE = (l & 7) * 8;

  // phase 1a: async stage v[128][64] + prefetch waoT k0=0 into Bs0
  const unsigned short* vbase = qkv + (size_t)(b * NSEQ + n0) * 768 + 512 + h * 64;
  #pragma unroll
  for (int c = w; c < 16; c += 4)
    gload_lds16(vbase + (size_t)(c * 8 + crow) * 768 + ccolE, vlds + c * 512);
  #pragma unroll
  for (int c = w; c < 32; c += 4)
    gload_lds16(waoT + (size_t)(c * 8 + crow) * 256 + ccolE, Bs0 + c * 512);
  // phase 1b: reduce 32 slices; MT[d][e] = bf16( (sum Spart)[e][d] * 0.125 / dsum[e] )
  {
    int e = t >> 2, d0 = (t & 3) * 16;
    float dn = 0.f;
    #pragma unroll 8
    for (int sl = 0; sl < 32; ++sl) dn += dsum_part[(sl * 8 + bh) * 64 + e];
    float rdn = 0.125f / dn;
    #pragma unroll
    for (int i = 0; i < 16; i += 4){
      float4 mv = {0.f, 0.f, 0.f, 0.f};
      #pragma unroll 8
      for (int sl = 0; sl < 32; ++sl){
        float4 p = *(const float4*)(Spart + ((size_t)sl * 8 + bh) * 4096 + e * 64 + d0 + i);
        mv.x += p.x; mv.y += p.y; mv.z += p.z; mv.w += p.w;
      }
      mt[(d0 + i + 0) * 64 + e] = f2bf(mv.x * rdn);
      mt[(d0 + i + 1) * 64 + e] = f2bf(mv.y * rdn);
      mt[(d0 + i + 2) * 64 + e] = f2bf(mv.z * rdn);
      mt[(d0 + i + 3) * 64 + e] = f2bf(mv.w * rdn);
    }
  }
  __syncthreads();
  // phase 2: A = v @ MT ; wave w owns n-tiles {2w, 2w+1}; write As in reshape layout
  {
    f32x4 vacc[2][4];
    #pragma unroll
    for (int i = 0; i < 2; i++)
      #pragma unroll
      for (int j = 0; j < 4; j++) vacc[i][j] = (f32x4){0.f, 0.f, 0.f, 0.f};
    #pragma unroll
    for (int kk = 0; kk < 64; kk += 32){
      short8 vf[2], mf[4];
      #pragma unroll
      for (int i = 0; i < 2; i++)
        vf[i] = *(const short8*)&vlds[((w * 2 + i) * 16 + lr) * 64 + kk + kq * 8];
      #pragma unroll
      for (int j = 0; j < 4; j++)
        mf[j] = *(const short8*)&mt[(j * 16 + lr) * 64 + kk + kq * 8];
      #pragma unroll
      for (int i = 0; i < 2; i++)
        #pragma unroll
        for (int j = 0; j < 4; j++)
          vacc[i][j] = __builtin_amdgcn_mfma_f32_16x16x32_bf16(vf[i], mf[j], vacc[i][j], 0, 0, 0);
    }
    // n_loc = (2w+i)*16 + kq*4 + r -> As row (2w+i)*4+kq, col r*64 + j*16 + lr
    #pragma unroll
    for (int i = 0; i < 2; i++)
      #pragma unroll
      for (int j = 0; j < 4; j++)
        #pragma unroll
        for (int r = 0; r < 4; r++)
          As[((w * 2 + i) * 4 + kq) * 264 + r * 64 + j * 16 + lr] = f2bf(vacc[i][j][r]);
  }
  __syncthreads();   // As complete; Bs0 staged
  // phase 3: y = A @ waoT (K=256), Bs double-buffered 1-ahead
  f32x4 acc[2][4];
  #pragma unroll
  for (int i = 0; i < 2; i++)
    #pragma unroll
    for (int j = 0; j < 4; j++) acc[i][j] = (f32x4){0.f, 0.f, 0.f, 0.f};
  for (int s = 0; s < 4; ++s){
    const int cur = s & 1;
    if (s + 1 < 4){
      unsigned short* bnxt = Bs0 + (cur ^ 1) * 16384;
      #pragma unroll
      for (int c = w; c < 32; c += 4)
        gload_lds16(waoT + (size_t)(c * 8 + crow) * 256 + (s + 1) * 64 + ccolE,
                    bnxt + c * 512);
    }
    const unsigned short* bcur = Bs0 + cur * 16384;
    #pragma unroll
    for (int kk = 0; kk < 64; kk += 32){
      short8 af[2], bfr[4];
      #pragma unroll
      for (int i = 0; i < 2; i++)
        af[i] = *(const short8*)&As[(i * 16 + lr) * 264 + s * 64 + kk + kq * 8];
      #pragma unroll
      for (int j = 0; j < 4; j++)
        bfr[j] = *(const short8*)&bcur[(w * 64 + j * 16 + lr) * 64 + kk + kq * 8];
      #pragma unroll
      for (int i = 0; i < 2; i++)
        #pragma unroll
        for (int j = 0; j < 4; j++)
          acc[i][j] = __builtin_amdgcn_mfma_f32_16x16x32_bf16(af[i], bfr[j], acc[i][j], 0, 0, 0);
    }
    __syncthreads();
  }
  // phase 4: bias -> yt -> double LN -> residual
  #pragma unroll
  for (int i = 0; i < 2; i++)
    #pragma unroll
    for (int j = 0; j < 4; j++){
      float bv = bias[w * 64 + j * 16 + lr];
      #pragma unroll
      for (int r = 0; r < 4; r++)
        yt[(i * 16 + kq * 4 + r) * 260 + w * 64 + j * 16 + lr] = acc[i][j][r] + bv;
    }
  __syncthreads();
  const int gl = t & 63;
  #pragma unroll
  for (int rp = 0; rp < 8; rp++){
    int row = rp * 4 + (t >> 6);
    float4 v = *(const float4*)(yt + row * 260 + gl * 4);
    float mu = wsum(v.x + v.y + v.z + v.w) * 0.00390625f;
    float dx = v.x - mu, dy = v.y - mu, dz = v.z - mu, dw = v.w - mu;
    float rstd = rsqrtf(wsum(dx*dx + dy*dy + dz*dz + dw*dw) * 0.00390625f + EPSF);
    float4 ga = *(const float4*)(g_ao + gl * 4);
    float4 ba = *(const float4*)(be_ao + gl * 4);
    float zx = dx * rstd * ga.x + ba.x, zy = dy * rstd * ga.y + ba.y;
    float zz = dz * rstd * ga.z + ba.z, zw = dw * rstd * ga.w + ba.w;
    float mu2 = wsum(zx + zy + zz + zw) * 0.00390625f;
    float ex = zx - mu2, ey = zy - mu2, ez = zz - mu2, ew = zw - mu2;
    float rstd2 = rsqrtf(wsum(ex*ex + ey*ey + ez*ez + ew*ew) * 0.00390625f + EPSF);
    float4 gb = *(const float4*)(g1 + gl * 4);
    float4 bb = *(const float4*)(be1 + gl * 4);
    size_t off = (size_t)(m0 + row) * 256 + gl * 4;
    float4 xr = *(const float4*)(x + off);
    float hx = xr.x + ex * rstd2 * gb.x + bb.x;
    float hy = xr.y + ey * rstd2 * gb.y + bb.y;
    float hz = xr.z + ez * rstd2 * gb.z + bb.z;
    float hw = xr.w + ew * rstd2 * gb.w + bb.w;
    ushort4 hb; hb.x = f2bf(hx); hb.y = f2bf(hy); hb.z = f2bf(hz); hb.w = f2bf(hw);
    *(ushort4*)(hbf + off) = hb;
    float4 sv = {xr.x + hx, xr.y + hy, xr.z + hz, xr.w + hw};
    *(float4*)(sxh + off) = sv;
  }
}

// ------- fused fc2 GEMM + LN + residual: BM=16, grid 512 = 2 blocks/CU ------------
__global__ __launch_bounds__(256) void k_fc2_ln(
    const unsigned short* __restrict__ A, const unsigned short* __restrict__ BT,
    const float* __restrict__ bias, const float* __restrict__ sxh,
    const float* __restrict__ g2, const float* __restrict__ be2,
    float* __restrict__ out)
{
  constexpr int K = 1024;
  // LDS: As{0,1}[16*64] (4 KB) | Bs{0,1}[256*64] (64 KB); yt[16][260] aliases Bs
  __shared__ __align__(16) char smem[4096 + 65536];
  unsigned short* As0 = (unsigned short*)smem;              // +bsel*1024 shorts
  unsigned short* Bs0 = (unsigned short*)(smem + 4096);     // +bsel*16384 shorts
  float* yt = (float*)(smem + 4096);
  const int t = threadIdx.x, l = t & 63, w = t >> 6;
  const int lr = l & 15, kq = l >> 4;
  const int m0 = blockIdx.x * 16;
  const int crow = l >> 3, ccolE = (l & 7) * 8;
  f32x4 acc[4];
  #pragma unroll
  for (int j = 0; j < 4; j++) acc[j] = (f32x4){0.f, 0.f, 0.f, 0.f};

  auto stage = [&](int s, int bsel){
    if (w < 2)
      gload_lds16(A + (size_t)(m0 + w * 8 + crow) * K + s * 64 + ccolE,
                  As0 + bsel * 1024 + w * 512);
    unsigned short* bdst = Bs0 + bsel * 16384;
    #pragma unroll
    for (int c = w; c < 32; c += 4)
      gload_lds16(BT + (size_t)(c * 8 + crow) * K + s * 64 + ccolE, bdst + c * 512);
  };

  stage(0, 0);
  __syncthreads();
  for (int s = 0; s < 16; ++s){
    const int cur = s & 1;
    if (s + 1 < 16) stage(s + 1, cur ^ 1);
    const unsigned short* acur = As0 + cur * 1024;
    const unsigned short* bcur = Bs0 + cur * 16384;
    #pragma unroll
    for (int kk = 0; kk < 64; kk += 32){
      short8 af = *(const short8*)&acur[lr * 64 + kk + kq * 8];
      #pragma unroll
      for (int j = 0; j < 4; j++){
        short8 bfr = *(const short8*)&bcur[(w * 64 + j * 16 + lr) * 64 + kk + kq * 8];
        acc[j] = __builtin_amdgcn_mfma_f32_16x16x32_bf16(af, bfr, acc[j], 0, 0, 0);
      }
    }
    __syncthreads();
  }
  #pragma unroll
  for (int j = 0; j < 4; j++){
    float bv = bias[w * 64 + j * 16 + lr];
    #pragma unroll
    for (int r = 0; r < 4; r++)
      yt[(kq * 4 + r) * 260 + w * 64 + j * 16 + lr] = acc[j][r] + bv;
  }
  __syncthreads();
  const int gl = t & 63;
  #pragma unroll
  for (int rp = 0; rp < 4; rp++){
    int row = rp * 4 + (t >> 6);
    float4 v = *(const float4*)(yt + row * 260 + gl * 4);
    float mu = wsum(v.x + v.y + v.z + v.w) * 0.00390625f;
    float dx = v.x - mu, dy = v.y - mu, dz = v.z - mu, dw = v.w - mu;
    float rstd = rsqrtf(wsum(dx*dx + dy*dy + dz*dz + dw*dw) * 0.00390625f + EPSF);
    float4 g = *(const float4*)(g2 + gl * 4);
    float4 be = *(const float4*)(be2 + gl * 4);
    size_t off = (size_t)(m0 + row) * 256 + gl * 4;
    float4 sv = *(const float4*)(sxh + off);
    float4 o;
    o.x = sv.x + dx * rstd * g.x + be.x;
    o.y = sv.y + dy * rstd * g.y + be.y;
    o.z = sv.z + dz * rstd * g.z + be.z;
    o.w = sv.w + dw * rstd * g.w + be.w;
    *(float4*)(out + off) = o;
  }
}

extern "C" void kernel_launch(void* const* d_in, const int* in_sizes, int n_in,
                              void* d_out, int out_size, void* d_ws, size_t ws_size,
                              hipStream_t stream)
{
  const float* x     = (const float*)d_in[0];
  const float* w_qkv = (const float*)d_in[1];
  const float* w_ao  = (const float*)d_in[2];
  const float* b_ao  = (const float*)d_in[3];
  const float* g_ao  = (const float*)d_in[4];
  const float* be_ao = (const float*)d_in[5];
  const float* g1    = (const float*)d_in[6];
  const float* be1   = (const float*)d_in[7];
  const float* w_fc1 = (const float*)d_in[8];
  const float* b_fc1 = (const float*)d_in[9];
  const float* w_fc2 = (const float*)d_in[10];
  const float* b_fc2 = (const float*)d_in[11];
  const float* g2    = (const float*)d_in[12];
  const float* be2   = (const float*)d_in[13];
  float* out = (float*)d_out;
  char* ws = (char*)d_ws;

  unsigned short* qkv   = (unsigned short*)(ws + 0);          // [8192][768] bf16
  unsigned short* xbf   = (unsigned short*)(ws + 12582912);   // [8192][256] bf16; reused as hbf
  unsigned short* wqkvT = (unsigned short*)(ws + 16777216);   // [768][256]
  unsigned short* waoT  = (unsigned short*)(ws + 17170432);   // [256][256]
  unsigned short* wfc1T = (unsigned short*)(ws + 17301504);   // [1024][256]
  unsigned short* wfc2T = (unsigned short*)(ws + 17825792);   // [256][1024]
  float* Spart = (float*)(ws + 18350080);                     // [32][8][64][64] f32 (4.2 MB)
  float* dsum_part = (float*)(ws + 22544384);                 // [32][8][64]
  float* sxh   = (float*)(ws + 22609920);                     // [8192][256] f32
  unsigned short* mlp1 = (unsigned short*)(ws + 30998528);    // [8192][1024] bf16

  k_prep<<<2240, 256, 0, stream>>>(x, xbf, w_qkv, w_ao, w_fc1, w_fc2,
                                   wqkvT, waoT, wfc1T, wfc2T);

  // qkv = x @ w_qkv (no bias), bf16 out
  k_gemm<128, 128, false, false, true><<<dim3(6, 64), 256, 0, stream>>>(
      xbf, wqkvT, nullptr, nullptr, qkv, R_TOT, 768, 256);

  // M partial sums via MFMA (32 slices x 8 bh, 2 chunks in-register)
  k_msum<<<dim3(32, 8), 256, 0, stream>>>(qkv, Spart, dsum_part);

  // fused: reduce -> A = v@M' -> y1 = A@w_ao + b_ao -> h = x + LN(LN(y1)) -> hbf, sxh
  k_projvm_dln<<<256, 256, 0, stream>>>(qkv, Spart, dsum_part, waoT, b_ao, x,
                                        g_ao, be_ao, g1, be1, xbf, sxh);

  // mlp1 = gelu(h @ w_fc1 + b_fc1), bf16 out
  k_gemm<128, 128, true, true, true><<<dim3(8, 64), 256, 0, stream>>>(
      xbf, wfc1T, b_fc1, nullptr, mlp1, R_TOT, 1024, 256);

  // fused: out = sxh + LN(mlp1@w_fc2 + b_fc2) — BM=16, 512 blocks
  k_fc2_ln<<<512, 256, 0, stream>>>(mlp1, wfc2T, b_fc2, sxh, g2, be2, out);
}

// Round 14
// 77.619 us; speedup vs baseline: 1.1610x; 1.1610x over previous
//
#include <hip/hip_runtime.h>

typedef __attribute__((ext_vector_type(8))) short short8;
typedef __attribute__((ext_vector_type(4))) float f32x4;

#define EPSF 1e-5f
#define NSEQ 4096
#define R_TOT 8192

__device__ __forceinline__ float bf2f(unsigned short u){
  union { unsigned int i; float f; } v; v.i = ((unsigned int)u) << 16; return v.f;
}
__device__ __forceinline__ unsigned short f2bf(float f){
  union { float f; unsigned int i; } v; v.f = f;
  unsigned int u = v.i;
  u += 0x7FFFu + ((u >> 16) & 1u);          // RNE
  return (unsigned short)(u >> 16);
}
__device__ __forceinline__ float wsum(float v){
  #pragma unroll
  for (int o = 32; o > 0; o >>= 1) v += __shfl_xor(v, o, 64);
  return v;
}
// fast tanh-GELU: tanh(y) = 1 - 2/(exp(2y)+1); inf-safe at both tails
__device__ __forceinline__ float gelu_tanh(float x){
  float y = 0.7978845608028654f * (x + 0.044715f * x * x * x);
  float e = __expf(2.0f * y);
  float th = 1.0f - 2.0f / (e + 1.0f);
  return 0.5f * x * (1.0f + th);
}
__device__ __forceinline__ void gload_lds16(const unsigned short* g, unsigned short* l){
  __builtin_amdgcn_global_load_lds(
      (const __attribute__((address_space(1))) unsigned int*)g,
      (__attribute__((address_space(3))) unsigned int*)l, 16, 0, 0);
}

// ------ prep: x->bf16 (0..2047) + 4 weight transposes (2048..2239) ----------------
__global__ void k_prep(const float* __restrict__ x, unsigned short* __restrict__ xbf,
                       const float* __restrict__ w_qkv, const float* __restrict__ w_ao,
                       const float* __restrict__ w_fc1, const float* __restrict__ w_fc2,
                       unsigned short* __restrict__ oq, unsigned short* __restrict__ oa,
                       unsigned short* __restrict__ o1, unsigned short* __restrict__ o2)
{
  int bid = blockIdx.x;
  const int t = threadIdx.x;
  if (bid < 2048){
    int i = (bid * 256 + t) * 4;
    float4 v = *(const float4*)(x + i);
    ushort4 o;
    o.x = f2bf(v.x); o.y = f2bf(v.y); o.z = f2bf(v.z); o.w = f2bf(v.w);
    *(ushort4*)(xbf + i) = o;
    return;
  }
  bid -= 2048;
  const float* in; unsigned short* out; int rows, cols, tid;
  if (bid < 48)      { in = w_qkv; out = oq; rows = 256;  cols = 768;  tid = bid; }
  else if (bid < 64) { in = w_ao;  out = oa; rows = 256;  cols = 256;  tid = bid - 48; }
  else if (bid < 128){ in = w_fc1; out = o1; rows = 256;  cols = 1024; tid = bid - 64; }
  else               { in = w_fc2; out = o2; rows = 1024; cols = 256;  tid = bid - 128; }
  const int tC = cols >> 6;
  const int r0 = (tid / tC) * 64, c0 = (tid % tC) * 64;
  __shared__ float tile[64][68];
  const int i = t >> 4, j4 = (t & 15) * 4;
  #pragma unroll
  for (int p = 0; p < 4; p++){
    float4 v = *(const float4*)(in + (size_t)(r0 + i + p * 16) * cols + c0 + j4);
    tile[i + p * 16][j4 + 0] = v.x; tile[i + p * 16][j4 + 1] = v.y;
    tile[i + p * 16][j4 + 2] = v.z; tile[i + p * 16][j4 + 3] = v.w;
  }
  __syncthreads();
  #pragma unroll
  for (int p = 0; p < 4; p++){
    int ci = i + p * 16;
    ushort4 o;
    o.x = f2bf(tile[j4 + 0][ci]); o.y = f2bf(tile[j4 + 1][ci]);
    o.z = f2bf(tile[j4 + 2][ci]); o.w = f2bf(tile[j4 + 3][ci]);
    *(ushort4*)(out + (size_t)(c0 + ci) * rows + r0 + j4) = o;
  }
}

// -------- bf16 MFMA GEMM, 2-phase double-buffered staging (T3-minimum) ------------
template<int BM, int BN, bool HAS_BIAS, bool DO_GELU, bool OUT_BF16>
__global__ __launch_bounds__(256) void k_gemm(const unsigned short* __restrict__ A,
                       const unsigned short* __restrict__ BT,
                       const float* __restrict__ bias,
                       float* __restrict__ Cf,
                       unsigned short* __restrict__ Cb,
                       int M, int N, int K)
{
  constexpr int BK = 64;
  constexpr int FM = BM / 32, FN = BN / 32;
  __shared__ unsigned short As[2][BM * BK];
  __shared__ unsigned short Bs[2][BN * BK];
  const int t  = threadIdx.x;
  const int l  = t & 63;
  const int w  = t >> 6;
  const int wm = w >> 1, wn = w & 1;
  const int lr = l & 15, kq = l >> 4;
  const int m0 = blockIdx.y * BM, n0 = blockIdx.x * BN;

  f32x4 acc[FM][FN];
  #pragma unroll
  for (int i = 0; i < FM; i++)
    #pragma unroll
    for (int j = 0; j < FN; j++) acc[i][j] = (f32x4){0.f, 0.f, 0.f, 0.f};

  const int crow = l >> 3, ccolE = (l & 7) * 8;
  const int nk = K / BK;

  auto stage = [&](int s, int bsel){
    #pragma unroll
    for (int c = w; c < BM / 8; c += 4)
      gload_lds16(A  + (size_t)(m0 + c * 8 + crow) * K + s * BK + ccolE, &As[bsel][c * 512]);
    #pragma unroll
    for (int c = w; c < BN / 8; c += 4)
      gload_lds16(BT + (size_t)(n0 + c * 8 + crow) * K + s * BK + ccolE, &Bs[bsel][c * 512]);
  };

  stage(0, 0);
  __syncthreads();
  for (int s = 0; s < nk; ++s){
    const int cur = s & 1;
    if (s + 1 < nk) stage(s + 1, cur ^ 1);
    #pragma unroll
    for (int kk = 0; kk < BK; kk += 32){
      short8 af[FM], bfr[FN];
      #pragma unroll
      for (int i = 0; i < FM; i++)
        af[i]  = *(const short8*)&As[cur][(wm * (BM / 2) + i * 16 + lr) * 64 + kk + kq * 8];
      #pragma unroll
      for (int j = 0; j < FN; j++)
        bfr[j] = *(const short8*)&Bs[cur][(wn * (BN / 2) + j * 16 + lr) * 64 + kk + kq * 8];
      #pragma unroll
      for (int i = 0; i < FM; i++)
        #pragma unroll
        for (int j = 0; j < FN; j++)
          acc[i][j] = __builtin_amdgcn_mfma_f32_16x16x32_bf16(af[i], bfr[j], acc[i][j], 0, 0, 0);
    }
    __syncthreads();
  }

  const int row0 = m0 + wm * (BM / 2);
  const int col0 = n0 + wn * (BN / 2);
  #pragma unroll
  for (int i = 0; i < FM; i++){
    #pragma unroll
    for (int j = 0; j < FN; j++){
      #pragma unroll
      for (int r = 0; r < 4; r++){
        int row = row0 + i * 16 + kq * 4 + r;
        int col = col0 + j * 16 + lr;
        float v = acc[i][j][r];
        if (HAS_BIAS) v += bias[col];
        if (DO_GELU)  v = gelu_tanh(v);
        if (OUT_BF16) Cb[(size_t)row * N + col] = f2bf(v);
        else          Cf[(size_t)row * N + col] = v;
      }
    }
  }
}

// ---- MFMA M-sum: Spart[sl][bh][e][d] = sum over 64 rows of exp(k[n,e]) q[n,d] ----
// grid (64,8), 256 threads (4 waves); wave w owns C-rows [16w,16w+16). Ones-row
// appended to qT gives the softmax denominator as C-tile j=4.
#define NPAD 72
__global__ __launch_bounds__(256) void k_msum(const unsigned short* __restrict__ qkv,
                                              float* __restrict__ Spart,
                                              float* __restrict__ dsum_part)
{
  __shared__ unsigned short kT[64 * NPAD];
  __shared__ unsigned short qT[80 * NPAD];
  const int t = threadIdx.x;          // 0..255
  const int sl = blockIdx.x;          // 0..63
  const int bh = blockIdx.y;          // 0..7
  const int b = bh >> 2, h = bh & 3;
  const int e4 = (t & 15) * 4;
  const int col = (t >> 4) * 4;       // 0,4,...,60
  {
    int n = sl * 64 + col;
    const unsigned short* rp = qkv + (size_t)(b * NSEQ + n) * 768 + h * 64 + e4;
    ushort4 q0 = *(const ushort4*)(rp);
    ushort4 q1 = *(const ushort4*)(rp + 768);
    ushort4 q2 = *(const ushort4*)(rp + 1536);
    ushort4 q3 = *(const ushort4*)(rp + 2304);
    ushort4 k0 = *(const ushort4*)(rp + 256);
    ushort4 k1 = *(const ushort4*)(rp + 1024);
    ushort4 k2 = *(const ushort4*)(rp + 1792);
    ushort4 k3 = *(const ushort4*)(rp + 2560);
    ushort4 w;
    w.x = q0.x; w.y = q1.x; w.z = q2.x; w.w = q3.x; *(ushort4*)&qT[(e4+0)*NPAD + col] = w;
    w.x = q0.y; w.y = q1.y; w.z = q2.y; w.w = q3.y; *(ushort4*)&qT[(e4+1)*NPAD + col] = w;
    w.x = q0.z; w.y = q1.z; w.z = q2.z; w.w = q3.z; *(ushort4*)&qT[(e4+2)*NPAD + col] = w;
    w.x = q0.w; w.y = q1.w; w.z = q2.w; w.w = q3.w; *(ushort4*)&qT[(e4+3)*NPAD + col] = w;
    w.x = f2bf(__expf(bf2f(k0.x))); w.y = f2bf(__expf(bf2f(k1.x)));
    w.z = f2bf(__expf(bf2f(k2.x))); w.w = f2bf(__expf(bf2f(k3.x)));
    *(ushort4*)&kT[(e4+0)*NPAD + col] = w;
    w.x = f2bf(__expf(bf2f(k0.y))); w.y = f2bf(__expf(bf2f(k1.y)));
    w.z = f2bf(__expf(bf2f(k2.y))); w.w = f2bf(__expf(bf2f(k3.y)));
    *(ushort4*)&kT[(e4+1)*NPAD + col] = w;
    w.x = f2bf(__expf(bf2f(k0.z))); w.y = f2bf(__expf(bf2f(k1.z)));
    w.z = f2bf(__expf(bf2f(k2.z))); w.w = f2bf(__expf(bf2f(k3.z)));
    *(ushort4*)&kT[(e4+2)*NPAD + col] = w;
    w.x = f2bf(__expf(bf2f(k0.w))); w.y = f2bf(__expf(bf2f(k1.w)));
    w.z = f2bf(__expf(bf2f(k2.w))); w.w = f2bf(__expf(bf2f(k3.w)));
    *(ushort4*)&kT[(e4+3)*NPAD + col] = w;
  }
  if (t < 16){
    ushort4 ones; ones.x = 0x3F80; ones.y = 0x3F80; ones.z = 0x3F80; ones.w = 0x3F80;
    *(ushort4*)&qT[64 * NPAD + t * 4] = ones;
  }
  __syncthreads();
  const int w4 = t >> 6, lr = t & 15, kq = (t >> 4) & 3;
  f32x4 acc[5];
  #pragma unroll
  for (int j = 0; j < 5; ++j) acc[j] = (f32x4){0.f, 0.f, 0.f, 0.f};
  #pragma unroll
  for (int ks = 0; ks < 2; ++ks){
    int nc = ks * 32 + kq * 8;
    short8 af = *(const short8*)&kT[(w4 * 16 + lr) * NPAD + nc];
    #pragma unroll
    for (int j = 0; j < 5; ++j){
      short8 bf = *(const short8*)&qT[(j * 16 + lr) * NPAD + nc];
      acc[j] = __builtin_amdgcn_mfma_f32_16x16x32_bf16(af, bf, acc[j], 0, 0, 0);
    }
  }
  float* sp = Spart + ((size_t)sl * 8 + bh) * 4096;
  #pragma unroll
  for (int j = 0; j < 4; ++j)
    #pragma unroll
    for (int r = 0; r < 4; ++r)
      sp[(w4 * 16 + kq * 4 + r) * 64 + j * 16 + lr] = acc[j][r];
  if (lr == 0){
    float* dp = dsum_part + (sl * 8 + bh) * 64;
    #pragma unroll
    for (int r = 0; r < 4; ++r) dp[w4 * 16 + kq * 4 + r] = acc[4][r];
  }
}

// ---------------- reduce 64 slices: Mm raw sums; dsumb denominators ----------------
__global__ void k_mreduce(const float* __restrict__ Spart, const float* __restrict__ dsum_part,
                          float* __restrict__ Mm, float* __restrict__ dsumb){
  int bid = blockIdx.x, t = threadIdx.x;
  if (bid < 128){
    int idx = bid * 256 + t;
    float s = 0.f;
    #pragma unroll 8
    for (int sl = 0; sl < 64; ++sl) s += Spart[(size_t)sl * 32768 + idx];
    Mm[idx] = s;
  } else {
    int oi = (bid - 128) * 256 + t;
    float s = 0.f;
    #pragma unroll 8
    for (int sl = 0; sl < 64; ++sl) s += dsum_part[sl * 512 + oi];
    dsumb[oi] = s;
  }
}

// ------ fused: M' -> A = v@M' -> y = A@w_ao + b_ao -> double-LN + resid ----------
__global__ __launch_bounds__(256) void k_projvm_dln(
    const unsigned short* __restrict__ qkv,
    const float* __restrict__ Mm, const float* __restrict__ dsumb,
    const unsigned short* __restrict__ waoT,
    const float* __restrict__ bias, const float* __restrict__ x,
    const float* __restrict__ g_ao, const float* __restrict__ be_ao,
    const float* __restrict__ g1, const float* __restrict__ be1,
    unsigned short* __restrict__ hbf, float* __restrict__ sxh)
{
  // LDS: As[32][264] | vlds[128][64] | mt[64][64] | Bs{0,1}[256][64] (yt aliases Bs)
  __shared__ __align__(16) char smem[16896 + 16384 + 8192 + 65536];
  unsigned short* As   = (unsigned short*)smem;                       // stride 264
  unsigned short* vlds = (unsigned short*)(smem + 16896);
  unsigned short* mt   = (unsigned short*)(smem + 16896 + 16384);
  unsigned short* Bs0  = (unsigned short*)(smem + 41472);             // +bsel*16384 shorts
  float*          yt   = (float*)(smem + 41472);

  const int t = threadIdx.x, l = t & 63, w = t >> 6;
  const int lr = l & 15, kq = l >> 4;
  const int m0 = blockIdx.x * 32;
  const int b = m0 >> 12, h = (m0 >> 10) & 3;
  const int bh = b * 4 + h;
  const int n0 = (m0 & 1023) * 4;
  const int crow = l >> 3, ccolE = (l & 7) * 8;

  // phase 1a: async stage v[128][64] + prefetch waoT k0=0 into Bs0
  const unsigned short* vbase = qkv + (size_t)(b * NSEQ + n0) * 768 + 512 + h * 64;
  #pragma unroll
  for (int c = w; c < 16; c += 4)
    gload_lds16(vbase + (size_t)(c * 8 + crow) * 768 + ccolE, vlds + c * 512);
  #pragma unroll
  for (int c = w; c < 32; c += 4)
    gload_lds16(waoT + (size_t)(c * 8 + crow) * 256 + ccolE, Bs0 + c * 512);
  // phase 1b: MT[d][e] = bf16( Mm[e][d] * 0.125 / dsum[e] )
  {
    int e = t >> 2, d0 = (t & 3) * 16;
    float rdn = 0.125f / dsumb[bh * 64 + e];
    const float* mp = Mm + (size_t)bh * 4096 + e * 64 + d0;
    #pragma unroll
    for (int i = 0; i < 16; i += 4){
      float4 mv = *(const float4*)(mp + i);
      mt[(d0 + i + 0) * 64 + e] = f2bf(mv.x * rdn);
      mt[(d0 + i + 1) * 64 + e] = f2bf(mv.y * rdn);
      mt[(d0 + i + 2) * 64 + e] = f2bf(mv.z * rdn);
      mt[(d0 + i + 3) * 64 + e] = f2bf(mv.w * rdn);
    }
  }
  __syncthreads();
  // phase 2: A = v @ MT ; wave w owns n-tiles {2w, 2w+1}; write As in reshape layout
  {
    f32x4 vacc[2][4];
    #pragma unroll
    for (int i = 0; i < 2; i++)
      #pragma unroll
      for (int j = 0; j < 4; j++) vacc[i][j] = (f32x4){0.f, 0.f, 0.f, 0.f};
    #pragma unroll
    for (int kk = 0; kk < 64; kk += 32){
      short8 vf[2], mf[4];
      #pragma unroll
      for (int i = 0; i < 2; i++)
        vf[i] = *(const short8*)&vlds[((w * 2 + i) * 16 + lr) * 64 + kk + kq * 8];
      #pragma unroll
      for (int j = 0; j < 4; j++)
        mf[j] = *(const short8*)&mt[(j * 16 + lr) * 64 + kk + kq * 8];
      #pragma unroll
      for (int i = 0; i < 2; i++)
        #pragma unroll
        for (int j = 0; j < 4; j++)
          vacc[i][j] = __builtin_amdgcn_mfma_f32_16x16x32_bf16(vf[i], mf[j], vacc[i][j], 0, 0, 0);
    }
    // n_loc = (2w+i)*16 + kq*4 + r -> As row (2w+i)*4+kq, col r*64 + j*16 + lr
    #pragma unroll
    for (int i = 0; i < 2; i++)
      #pragma unroll
      for (int j = 0; j < 4; j++)
        #pragma unroll
        for (int r = 0; r < 4; r++)
          As[((w * 2 + i) * 4 + kq) * 264 + r * 64 + j * 16 + lr] = f2bf(vacc[i][j][r]);
  }
  __syncthreads();   // As complete; Bs0 staged
  // phase 3: y = A @ waoT (K=256), Bs double-buffered 1-ahead
  f32x4 acc[2][4];
  #pragma unroll
  for (int i = 0; i < 2; i++)
    #pragma unroll
    for (int j = 0; j < 4; j++) acc[i][j] = (f32x4){0.f, 0.f, 0.f, 0.f};
  for (int s = 0; s < 4; ++s){
    const int cur = s & 1;
    if (s + 1 < 4){
      unsigned short* bnxt = Bs0 + (cur ^ 1) * 16384;
      #pragma unroll
      for (int c = w; c < 32; c += 4)
        gload_lds16(waoT + (size_t)(c * 8 + crow) * 256 + (s + 1) * 64 + ccolE,
                    bnxt + c * 512);
    }
    const unsigned short* bcur = Bs0 + cur * 16384;
    #pragma unroll
    for (int kk = 0; kk < 64; kk += 32){
      short8 af[2], bfr[4];
      #pragma unroll
      for (int i = 0; i < 2; i++)
        af[i] = *(const short8*)&As[(i * 16 + lr) * 264 + s * 64 + kk + kq * 8];
      #pragma unroll
      for (int j = 0; j < 4; j++)
        bfr[j] = *(const short8*)&bcur[(w * 64 + j * 16 + lr) * 64 + kk + kq * 8];
      #pragma unroll
      for (int i = 0; i < 2; i++)
        #pragma unroll
        for (int j = 0; j < 4; j++)
          acc[i][j] = __builtin_amdgcn_mfma_f32_16x16x32_bf16(af[i], bfr[j], acc[i][j], 0, 0, 0);
    }
    __syncthreads();
  }
  // phase 4: bias -> yt -> double LN -> residual
  #pragma unroll
  for (int i = 0; i < 2; i++)
    #pragma unroll
    for (int j = 0; j < 4; j++){
      float bv = bias[w * 64 + j * 16 + lr];
      #pragma unroll
      for (int r = 0; r < 4; r++)
        yt[(i * 16 + kq * 4 + r) * 260 + w * 64 + j * 16 + lr] = acc[i][j][r] + bv;
    }
  __syncthreads();
  const int gl = t & 63;
  #pragma unroll
  for (int rp = 0; rp < 8; rp++){
    int row = rp * 4 + (t >> 6);
    float4 v = *(const float4*)(yt + row * 260 + gl * 4);
    float mu = wsum(v.x + v.y + v.z + v.w) * 0.00390625f;
    float dx = v.x - mu, dy = v.y - mu, dz = v.z - mu, dw = v.w - mu;
    float rstd = rsqrtf(wsum(dx*dx + dy*dy + dz*dz + dw*dw) * 0.00390625f + EPSF);
    float4 ga = *(const float4*)(g_ao + gl * 4);
    float4 ba = *(const float4*)(be_ao + gl * 4);
    float zx = dx * rstd * ga.x + ba.x, zy = dy * rstd * ga.y + ba.y;
    float zz = dz * rstd * ga.z + ba.z, zw = dw * rstd * ga.w + ba.w;
    float mu2 = wsum(zx + zy + zz + zw) * 0.00390625f;
    float ex = zx - mu2, ey = zy - mu2, ez = zz - mu2, ew = zw - mu2;
    float rstd2 = rsqrtf(wsum(ex*ex + ey*ey + ez*ez + ew*ew) * 0.00390625f + EPSF);
    float4 gb = *(const float4*)(g1 + gl * 4);
    float4 bb = *(const float4*)(be1 + gl * 4);
    size_t off = (size_t)(m0 + row) * 256 + gl * 4;
    float4 xr = *(const float4*)(x + off);
    float hx = xr.x + ex * rstd2 * gb.x + bb.x;
    float hy = xr.y + ey * rstd2 * gb.y + bb.y;
    float hz = xr.z + ez * rstd2 * gb.z + bb.z;
    float hw = xr.w + ew * rstd2 * gb.w + bb.w;
    ushort4 hb; hb.x = f2bf(hx); hb.y = f2bf(hy); hb.z = f2bf(hz); hb.w = f2bf(hw);
    *(ushort4*)(hbf + off) = hb;
    float4 sv = {xr.x + hx, xr.y + hy, xr.z + hz, xr.w + hw};
    *(float4*)(sxh + off) = sv;
  }
}

// ------- fused fc2 GEMM + LN + residual: BM=16, grid 512 = 2 blocks/CU ------------
__global__ __launch_bounds__(256) void k_fc2_ln(
    const unsigned short* __restrict__ A, const unsigned short* __restrict__ BT,
    const float* __restrict__ bias, const float* __restrict__ sxh,
    const float* __restrict__ g2, const float* __restrict__ be2,
    float* __restrict__ out)
{
  constexpr int K = 1024;
  // LDS: As{0,1}[16*64] (4 KB) | Bs{0,1}[256*64] (64 KB); yt[16][260] aliases Bs
  __shared__ __align__(16) char smem[4096 + 65536];
  unsigned short* As0 = (unsigned short*)smem;              // +bsel*1024 shorts
  unsigned short* Bs0 = (unsigned short*)(smem + 4096);     // +bsel*16384 shorts
  float* yt = (float*)(smem + 4096);
  const int t = threadIdx.x, l = t & 63, w = t >> 6;
  const int lr = l & 15, kq = l >> 4;
  const int m0 = blockIdx.x * 16;
  const int crow = l >> 3, ccolE = (l & 7) * 8;
  f32x4 acc[4];
  #pragma unroll
  for (int j = 0; j < 4; j++) acc[j] = (f32x4){0.f, 0.f, 0.f, 0.f};

  auto stage = [&](int s, int bsel){
    if (w < 2)
      gload_lds16(A + (size_t)(m0 + w * 8 + crow) * K + s * 64 + ccolE,
                  As0 + bsel * 1024 + w * 512);
    unsigned short* bdst = Bs0 + bsel * 16384;
    #pragma unroll
    for (int c = w; c < 32; c += 4)
      gload_lds16(BT + (size_t)(c * 8 + crow) * K + s * 64 + ccolE, bdst + c * 512);
  };

  stage(0, 0);
  __syncthreads();
  for (int s = 0; s < 16; ++s){
    const int cur = s & 1;
    if (s + 1 < 16) stage(s + 1, cur ^ 1);
    const unsigned short* acur = As0 + cur * 1024;
    const unsigned short* bcur = Bs0 + cur * 16384;
    #pragma unroll
    for (int kk = 0; kk < 64; kk += 32){
      short8 af = *(const short8*)&acur[lr * 64 + kk + kq * 8];
      #pragma unroll
      for (int j = 0; j < 4; j++){
        short8 bfr = *(const short8*)&bcur[(w * 64 + j * 16 + lr) * 64 + kk + kq * 8];
        acc[j] = __builtin_amdgcn_mfma_f32_16x16x32_bf16(af, bfr, acc[j], 0, 0, 0);
      }
    }
    __syncthreads();
  }
  #pragma unroll
  for (int j = 0; j < 4; j++){
    float bv = bias[w * 64 + j * 16 + lr];
    #pragma unroll
    for (int r = 0; r < 4; r++)
      yt[(kq * 4 + r) * 260 + w * 64 + j * 16 + lr] = acc[j][r] + bv;
  }
  __syncthreads();
  const int gl = t & 63;
  #pragma unroll
  for (int rp = 0; rp < 4; rp++){
    int row = rp * 4 + (t >> 6);
    float4 v = *(const float4*)(yt + row * 260 + gl * 4);
    float mu = wsum(v.x + v.y + v.z + v.w) * 0.00390625f;
    float dx = v.x - mu, dy = v.y - mu, dz = v.z - mu, dw = v.w - mu;
    float rstd = rsqrtf(wsum(dx*dx + dy*dy + dz*dz + dw*dw) * 0.00390625f + EPSF);
    float4 g = *(const float4*)(g2 + gl * 4);
    float4 be = *(const float4*)(be2 + gl * 4);
    size_t off = (size_t)(m0 + row) * 256 + gl * 4;
    float4 sv = *(const float4*)(sxh + off);
    float4 o;
    o.x = sv.x + dx * rstd * g.x + be.x;
    o.y = sv.y + dy * rstd * g.y + be.y;
    o.z = sv.z + dz * rstd * g.z + be.z;
    o.w = sv.w + dw * rstd * g.w + be.w;
    *(float4*)(out + off) = o;
  }
}

extern "C" void kernel_launch(void* const* d_in, const int* in_sizes, int n_in,
                              void* d_out, int out_size, void* d_ws, size_t ws_size,
                              hipStream_t stream)
{
  const float* x     = (const float*)d_in[0];
  const float* w_qkv = (const float*)d_in[1];
  const float* w_ao  = (const float*)d_in[2];
  const float* b_ao  = (const float*)d_in[3];
  const float* g_ao  = (const float*)d_in[4];
  const float* be_ao = (const float*)d_in[5];
  const float* g1    = (const float*)d_in[6];
  const float* be1   = (const float*)d_in[7];
  const float* w_fc1 = (const float*)d_in[8];
  const float* b_fc1 = (const float*)d_in[9];
  const float* w_fc2 = (const float*)d_in[10];
  const float* b_fc2 = (const float*)d_in[11];
  const float* g2    = (const float*)d_in[12];
  const float* be2   = (const float*)d_in[13];
  float* out = (float*)d_out;
  char* ws = (char*)d_ws;

  unsigned short* qkv   = (unsigned short*)(ws + 0);          // [8192][768] bf16
  unsigned short* xbf   = (unsigned short*)(ws + 12582912);   // [8192][256] bf16; reused as hbf
  unsigned short* wqkvT = (unsigned short*)(ws + 16777216);   // [768][256]
  unsigned short* waoT  = (unsigned short*)(ws + 17170432);   // [256][256]
  unsigned short* wfc1T = (unsigned short*)(ws + 17301504);   // [1024][256]
  unsigned short* wfc2T = (unsigned short*)(ws + 17825792);   // [256][1024]
  float* Spart = (float*)(ws + 18350080);                     // [64][8][64][64] f32 (8.4 MB)
  float* dsum_part = (float*)(ws + 26738688);                 // [64][8][64]
  float* Mm    = (float*)(ws + 26869760);                     // [8][64][64]
  float* dsumb = (float*)(ws + 27000832);                     // [8][64]
  float* sxh   = (float*)(ws + 27004928);                     // [8192][256] f32
  unsigned short* mlp1 = (unsigned short*)(ws + 35393536);    // [8192][1024] bf16

  k_prep<<<2240, 256, 0, stream>>>(x, xbf, w_qkv, w_ao, w_fc1, w_fc2,
                                   wqkvT, waoT, wfc1T, wfc2T);

  // qkv = x @ w_qkv (no bias), bf16 out
  k_gemm<128, 128, false, false, true><<<dim3(6, 64), 256, 0, stream>>>(
      xbf, wqkvT, nullptr, nullptr, qkv, R_TOT, 768, 256);

  // M partial sums via MFMA (64 slices x 8 bh, 4 waves each)
  k_msum<<<dim3(64, 8), 256, 0, stream>>>(qkv, Spart, dsum_part);
  k_mreduce<<<130, 256, 0, stream>>>(Spart, dsum_part, Mm, dsumb);

  // fused: A = v@M' -> y1 = A@w_ao + b_ao -> h = x + LN(LN(y1)) -> hbf, sxh
  k_projvm_dln<<<256, 256, 0, stream>>>(qkv, Mm, dsumb, waoT, b_ao, x,
                                        g_ao, be_ao, g1, be1, xbf, sxh);

  // mlp1 = gelu(h @ w_fc1 + b_fc1), bf16 out
  k_gemm<128, 128, true, true, true><<<dim3(8, 64), 256, 0, stream>>>(
      xbf, wfc1T, b_fc1, nullptr, mlp1, R_TOT, 1024, 256);

  // fused: out = sxh + LN(mlp1@w_fc2 + b_fc2) — BM=16, 512 blocks
  k_fc2_ln<<<512, 256, 0, stream>>>(mlp1, wfc2T, b_fc2, sxh, g2, be2, out);
}